// Round 11
// baseline (927.460 us; speedup 1.0000x reference)
//
#include <hip/hip_runtime.h>
#include <hip/hip_bf16.h>
#include <cstdint>
#include <cstddef>

using bf16 = __hip_bfloat16;

typedef __attribute__((ext_vector_type(8))) short short8;
typedef __attribute__((ext_vector_type(4))) float floatx4;

constexpr int NLAYERS = 2;
constexpr int D_MODEL = 512;
constexpr int NHEAD   = 8;
constexpr int DH      = 64;
constexpr int SEQ     = 2048;
constexpr int BATCH   = 4;
constexpr int D_FF    = 2048;
constexpr int ROWS    = BATCH * SEQ;  // 8192

#define MODE_QKV       0
#define MODE_RELU_BF16 1
#define MODE_F32       2

constexpr int BM = 128, BN = 128, BK = 64;
constexpr int LDT = BK + 8;

__device__ inline ushort4 pack4_bf16(float4 v) {
    ushort4 u;
    u.x = __bfloat16_as_ushort(__float2bfloat16(v.x));
    u.y = __bfloat16_as_ushort(__float2bfloat16(v.y));
    u.z = __bfloat16_as_ushort(__float2bfloat16(v.z));
    u.w = __bfloat16_as_ushort(__float2bfloat16(v.w));
    return u;
}

// C[M,N] = A[M,K] @ B[N,K]^T + bias. A fp32 ext (inline cvt) or bf16 ws; B,bias fp32.
__global__ __launch_bounds__(256) void gemm_bt(
    const bf16* __restrict__ Ab, const float* __restrict__ Af,
    const float* __restrict__ B, const float* __restrict__ bias,
    float* __restrict__ Cf, bf16* __restrict__ Cb,
    bf16* __restrict__ Qo, bf16* __restrict__ Ko, bf16* __restrict__ Vo,
    int M, int N, int K, int mode)
{
    __shared__ bf16 As[BM][LDT];
    __shared__ bf16 Bs[BN][LDT];
    const int tid  = threadIdx.x;
    const int bn   = blockIdx.x * BN;
    const int bm   = blockIdx.y * BM;
    const int lane = tid & 63;
    const int wave = tid >> 6;
    const int wm   = (wave & 1) * 64;
    const int wn   = (wave >> 1) * 64;

    floatx4 acc[4][4];
    #pragma unroll
    for (int i = 0; i < 4; i++)
        #pragma unroll
        for (int j = 0; j < 4; j++)
            acc[i][j] = (floatx4){0.f, 0.f, 0.f, 0.f};

    const int lr = tid >> 3;        // 0..31
    const int lc = (tid & 7) * 8;   // 0,8,..,56

    for (int k0 = 0; k0 < K; k0 += BK) {
        #pragma unroll
        for (int r = 0; r < BM; r += 32) {
            const size_t ra = (size_t)(bm + r + lr) * K + k0 + lc;
            if (Af) {
                float4 v0 = *(const float4*)(Af + ra);
                float4 v1 = *(const float4*)(Af + ra + 4);
                *(ushort4*)&As[r + lr][lc]     = pack4_bf16(v0);
                *(ushort4*)&As[r + lr][lc + 4] = pack4_bf16(v1);
            } else {
                *(uint4*)&As[r + lr][lc] = *(const uint4*)(Ab + ra);
            }
            const size_t rb_ = (size_t)(bn + r + lr) * K + k0 + lc;
            float4 w0 = *(const float4*)(B + rb_);
            float4 w1 = *(const float4*)(B + rb_ + 4);
            *(ushort4*)&Bs[r + lr][lc]     = pack4_bf16(w0);
            *(ushort4*)&Bs[r + lr][lc + 4] = pack4_bf16(w1);
        }
        __syncthreads();
        #pragma unroll
        for (int ks = 0; ks < BK; ks += 32) {
            const int kk = ks + (lane >> 4) * 8;
            const int ri = lane & 15;
            short8 af[4], bfr[4];
            #pragma unroll
            for (int i = 0; i < 4; i++) af[i]  = *(const short8*)&As[wm + i*16 + ri][kk];
            #pragma unroll
            for (int j = 0; j < 4; j++) bfr[j] = *(const short8*)&Bs[wn + j*16 + ri][kk];
            #pragma unroll
            for (int i = 0; i < 4; i++)
                #pragma unroll
                for (int j = 0; j < 4; j++)
                    acc[i][j] = __builtin_amdgcn_mfma_f32_16x16x32_bf16(af[i], bfr[j], acc[i][j], 0, 0, 0);
        }
        __syncthreads();
    }

    // C/D layout: col=lane&15, row=(lane>>4)*4+reg (m89/m91; r5 scalar-core-verified)
    const int cn = lane & 15;
    const int rb = (lane >> 4) * 4;
    #pragma unroll
    for (int j = 0; j < 4; j++) {
        const int col = bn + wn + j * 16 + cn;
        const float bv = bias[col];
        #pragma unroll
        for (int i = 0; i < 4; i++) {
            #pragma unroll
            for (int r = 0; r < 4; r++) {
                const int row = bm + wm + i * 16 + rb + r;
                float v = acc[i][j][r] + bv;
                if (mode == MODE_RELU_BF16) {
                    Cb[(size_t)row * N + col] = __float2bfloat16(fmaxf(v, 0.f));
                } else if (mode == MODE_F32) {
                    Cf[(size_t)row * N + col] = v;
                } else {  // QKV scatter -> [B,H,S,dh]
                    const int which = col >> 9;
                    const int f = col & 511;
                    const int h = f >> 6, d = f & 63;
                    const int b = row >> 11, s = row & (SEQ - 1);
                    bf16* dst = (which == 0) ? Qo : (which == 1) ? Ko : Vo;
                    dst[(((size_t)b * NHEAD + h) * SEQ + s) * DH + d] = __float2bfloat16(v);
                }
            }
        }
    }
}

__device__ inline float dot_qk(const float* qs, const bf16* kr) {
    float a = 0.f;
    #pragma unroll
    for (int c = 0; c < 8; c++) {
        uint4 d = *(const uint4*)(kr + c * 8);
        const bf16* kk = (const bf16*)&d;
        #pragma unroll
        for (int t = 0; t < 8; t++) a += qs[c * 8 + t] * __bfloat162float(kk[t]);
    }
    return a;
}

// One wave per query. Mask analytic: causal window 64 + pow2 lookbacks {128,256,512,1024}.
__global__ __launch_bounds__(256) void attn_sparse(
    const bf16* __restrict__ Q, const bf16* __restrict__ K,
    const bf16* __restrict__ V, bf16* __restrict__ O)
{
    __shared__ float qs[4][64];
    __shared__ float ps[4][80];
    __shared__ int   ksl[4][80];
    __shared__ int   nks[4];
    const int tid  = threadIdx.x;
    const int wave = tid >> 6;
    const int lane = tid & 63;
    const int gq   = blockIdx.x * 4 + wave;
    const int s    = gq & (SEQ - 1);
    const int bh   = gq >> 11;

    qs[wave][lane] = __bfloat162float(Q[(size_t)gq * DH + lane]);

    const int kw0 = (s - 64 > 0) ? (s - 64) : 0;
    const int wcount = s - kw0 + 1;
    for (int j = lane; j < wcount; j += 64) ksl[wave][j] = kw0 + j;
    if (lane == 0) {
        int nk = wcount;
        #pragma unroll
        for (int st = 128; st <= 1024; st <<= 1)
            if (s - st >= 0) ksl[wave][nk++] = s - st;
        nks[wave] = nk;                         // <= 69
    }
    __syncthreads();
    const int nk = nks[wave];

    const bf16* Kb = K + (size_t)bh * SEQ * DH;
    const float scale = 0.125f;
    float sc0 = -1e30f, sc1 = -1e30f;
    if (lane < nk)      sc0 = dot_qk(qs[wave], Kb + (size_t)ksl[wave][lane] * DH) * scale;
    if (lane + 64 < nk) sc1 = dot_qk(qs[wave], Kb + (size_t)ksl[wave][lane + 64] * DH) * scale;

    float m = fmaxf(sc0, sc1);
    #pragma unroll
    for (int off = 32; off; off >>= 1) m = fmaxf(m, __shfl_xor(m, off, 64));
    const float p0 = (lane < nk)      ? __expf(fminf(sc0 - m, 0.f)) : 0.f;
    const float p1 = (lane + 64 < nk) ? __expf(fminf(sc1 - m, 0.f)) : 0.f;
    float lsum = p0 + p1;
    #pragma unroll
    for (int off = 32; off; off >>= 1) lsum += __shfl_xor(lsum, off, 64);
    const float inv = 1.f / fmaxf(lsum, 1e-20f);
    ps[wave][lane] = p0 * inv;
    if (lane + 64 < nk) ps[wave][lane + 64] = p1 * inv;
    __syncthreads();

    const bf16* Vb = V + (size_t)bh * SEQ * DH;
    float o = 0.f;
    for (int j = 0; j < nk; j++)
        o += ps[wave][j] * __bfloat162float(Vb[(size_t)ksl[wave][j] * DH + lane]);

    const int b = bh >> 3, h = bh & 7;
    O[((size_t)(b * SEQ + s)) * D_MODEL + h * DH + lane] = __float2bfloat16(o);
}

// xout = LN(xin + t) * gamma + beta ; one block per row of 512.
// Residual xin: fp32 ext (xin_f) or bf16 ws (xin_b). Output: fp32 (xout_f,
// final layer -> d_out) else bf16 (xout_b).
__global__ __launch_bounds__(256) void ln_residual(
    const bf16* __restrict__ xin_b, const float* __restrict__ xin_f,
    const float* __restrict__ t,
    const float* __restrict__ gamma, const float* __restrict__ beta,
    bf16* __restrict__ xout_b, float* __restrict__ xout_f)
{
    const int row = blockIdx.x;
    const int tid = threadIdx.x;
    const size_t base = (size_t)row * D_MODEL;
    float x0, x1;
    if (xin_f != nullptr) {
        x0 = xin_f[base + tid];
        x1 = xin_f[base + tid + 256];
    } else {
        x0 = __bfloat162float(xin_b[base + tid]);
        x1 = __bfloat162float(xin_b[base + tid + 256]);
    }
    const float v0 = x0 + t[base + tid];
    const float v1 = x1 + t[base + tid + 256];
    float sum = v0 + v1;
    float sq  = v0 * v0 + v1 * v1;
    #pragma unroll
    for (int off = 32; off; off >>= 1) {
        sum += __shfl_xor(sum, off, 64);
        sq  += __shfl_xor(sq,  off, 64);
    }
    __shared__ float s1[4], s2[4];
    const int wave = tid >> 6, lane = tid & 63;
    if (lane == 0) { s1[wave] = sum; s2[wave] = sq; }
    __syncthreads();
    const float S1 = s1[0] + s1[1] + s1[2] + s1[3];
    const float S2 = s2[0] + s2[1] + s2[2] + s2[3];
    const float mean = S1 * (1.f / D_MODEL);
    const float var  = fmaxf(S2 * (1.f / D_MODEL) - mean * mean, 0.f);
    const float r    = rsqrtf(var + 1e-5f);
    const float o0 = (v0 - mean) * r * gamma[tid] + beta[tid];
    const float o1 = (v1 - mean) * r * gamma[tid + 256] + beta[tid + 256];
    if (xout_f != nullptr) {
        xout_f[base + tid]       = o0;
        xout_f[base + tid + 256] = o1;
    } else {
        xout_b[base + tid]       = __float2bfloat16(o0);
        xout_b[base + tid + 256] = __float2bfloat16(o1);
    }
}

extern "C" void kernel_launch(void* const* d_in, const int* in_sizes, int n_in,
                              void* d_out, int out_size, void* d_ws, size_t ws_size,
                              hipStream_t stream)
{
    // Inputs fp32 (device-verified r6/r8); OUTPUT fp32 (reference output dtype).
    const int want[12] = {1572864, 3072, 524288, 1024, 1024, 1024,
                          2097152, 4096, 2097152, 1024, 1024, 1024};
    int anchor = -1;
    for (int a = 2; a >= 1; --a) {
        if (n_in < a + 12) continue;
        bool ok = true;
        for (int i = 0; i < 12; i++) if (in_sizes[a + i] != want[i]) { ok = false; break; }
        if (ok) { anchor = a; break; }
    }
    if (anchor < 0) return;

    const float* src   = (const float*)d_in[0];
    const float* qkv_w = (const float*)d_in[anchor + 0];
    const float* qkv_b = (const float*)d_in[anchor + 1];
    const float* out_w = (const float*)d_in[anchor + 2];
    const float* out_b = (const float*)d_in[anchor + 3];
    const float* ln1_s = (const float*)d_in[anchor + 4];
    const float* ln1_b = (const float*)d_in[anchor + 5];
    const float* w1    = (const float*)d_in[anchor + 6];
    const float* b1    = (const float*)d_in[anchor + 7];
    const float* w2    = (const float*)d_in[anchor + 8];
    const float* b2    = (const float*)d_in[anchor + 9];
    const float* ln2_s = (const float*)d_in[anchor + 10];
    const float* ln2_b = (const float*)d_in[anchor + 11];
    float* out = (float*)d_out;   // fp32 output

    constexpr size_t MiB = 1024 * 1024;
    if (ws_size < 64 * MiB) return;
    char* p = (char*)d_ws;
    bf16*  Q  = (bf16*)(p);
    bf16*  Kt = (bf16*)(p + 8 * MiB);
    bf16*  V  = (bf16*)(p + 16 * MiB);
    bf16*  O  = (bf16*)(p + 24 * MiB);
    bf16*  Hb = (bf16*)(p);                 // 32 MiB, aliases Q..O (disjoint lifetimes)
    float* T  = (float*)(p + 32 * MiB);     // 16 MiB
    bf16*  xA = (bf16*)(p + 48 * MiB);
    bf16*  xB = (bf16*)(p + 56 * MiB);

    const bf16*  xb = nullptr;              // bf16 ws activation
    const float* xf = src;                  // fp32 external (layer 0 only)
    for (int l = 0; l < NLAYERS; ++l) {
        gemm_bt<<<dim3((3 * D_MODEL) / BN, ROWS / BM), 256, 0, stream>>>(
            xb, xf, qkv_w + (size_t)l * 3 * D_MODEL * D_MODEL, qkv_b + (size_t)l * 3 * D_MODEL,
            nullptr, nullptr, Q, Kt, V, ROWS, 3 * D_MODEL, D_MODEL, MODE_QKV);
        attn_sparse<<<dim3(BATCH * NHEAD * SEQ / 4), 256, 0, stream>>>(Q, Kt, V, O);
        gemm_bt<<<dim3(D_MODEL / BN, ROWS / BM), 256, 0, stream>>>(
            O, nullptr, out_w + (size_t)l * D_MODEL * D_MODEL, out_b + (size_t)l * D_MODEL,
            T, nullptr, nullptr, nullptr, nullptr, ROWS, D_MODEL, D_MODEL, MODE_F32);
        ln_residual<<<dim3(ROWS), 256, 0, stream>>>(
            xb, xf, T, ln1_s + (size_t)l * D_MODEL, ln1_b + (size_t)l * D_MODEL, xA, nullptr);
        gemm_bt<<<dim3(D_FF / BN, ROWS / BM), 256, 0, stream>>>(
            xA, nullptr, w1 + (size_t)l * D_FF * D_MODEL, b1 + (size_t)l * D_FF,
            nullptr, Hb, nullptr, nullptr, nullptr, ROWS, D_FF, D_MODEL, MODE_RELU_BF16);
        gemm_bt<<<dim3(D_MODEL / BN, ROWS / BM), 256, 0, stream>>>(
            Hb, nullptr, w2 + (size_t)l * D_MODEL * D_FF, b2 + (size_t)l * D_MODEL,
            T, nullptr, nullptr, nullptr, nullptr, ROWS, D_MODEL, D_FF, MODE_F32);
        if (l == NLAYERS - 1) {
            ln_residual<<<dim3(ROWS), 256, 0, stream>>>(
                xA, nullptr, T, ln2_s + (size_t)l * D_MODEL, ln2_b + (size_t)l * D_MODEL,
                nullptr, out);                       // FINAL: fp32 -> d_out
        } else {
            ln_residual<<<dim3(ROWS), 256, 0, stream>>>(
                xA, nullptr, T, ln2_s + (size_t)l * D_MODEL, ln2_b + (size_t)l * D_MODEL,
                xB, nullptr);
            xb = xB; xf = nullptr;
        }
    }
}

// Round 12
// 586.573 us; speedup vs baseline: 1.5812x; 1.5812x over previous
//
#include <hip/hip_runtime.h>
#include <hip/hip_bf16.h>
#include <cstdint>
#include <cstddef>

using bf16 = __hip_bfloat16;

typedef __attribute__((ext_vector_type(8))) short short8;
typedef __attribute__((ext_vector_type(4))) float floatx4;

constexpr int NLAYERS = 2;
constexpr int D_MODEL = 512;
constexpr int NHEAD   = 8;
constexpr int DH      = 64;
constexpr int SEQ     = 2048;
constexpr int BATCH   = 4;
constexpr int D_FF    = 2048;
constexpr int ROWS    = BATCH * SEQ;  // 8192

#define MODE_QKV   0
#define MODE_RELU  1
#define MODE_PLAIN 2

constexpr int BM = 128, BN = 128, BK = 64;

__device__ inline ushort4 pack4_bf16(float4 v) {
    ushort4 u;
    u.x = __bfloat16_as_ushort(__float2bfloat16(v.x));
    u.y = __bfloat16_as_ushort(__float2bfloat16(v.y));
    u.z = __bfloat16_as_ushort(__float2bfloat16(v.z));
    u.w = __bfloat16_as_ushort(__float2bfloat16(v.w));
    return u;
}

// async global->LDS DMA, 16 B/lane; LDS dest = wave-uniform base + lane*16
__device__ inline void gld16(const void* g, void* l) {
    __builtin_amdgcn_global_load_lds(
        (const __attribute__((address_space(1))) void*)(uintptr_t)g,
        (__attribute__((address_space(3))) void*)(uint32_t)(uintptr_t)l,
        16, 0, 0);
}

// fp32 -> bf16 converter (weights), 4 elems/thread
__global__ __launch_bounds__(256) void cvt_f32_bf16(
    const float* __restrict__ in, bf16* __restrict__ outp, int n)
{
    const int i = (blockIdx.x * 256 + threadIdx.x) * 4;
    if (i + 3 < n) {
        *(ushort4*)(outp + i) = pack4_bf16(*(const float4*)(in + i));
    } else {
        for (int j = i; j < n; j++) outp[j] = __float2bfloat16(in[j]);
    }
}

// C[M,N] = A[M,K] @ B[N,K]^T + bias. A bf16 ws (DMA) or fp32 ext (manual cvt);
// B bf16 (DMA); bias fp32; outputs bf16 (QKV scatter / relu / plain).
__global__ __launch_bounds__(256) void gemm_bt(
    const bf16* __restrict__ Ab, const float* __restrict__ Af,
    const bf16* __restrict__ Bw, const float* __restrict__ bias,
    bf16* __restrict__ Cb,
    bf16* __restrict__ Qo, bf16* __restrict__ Ko, bf16* __restrict__ Vo,
    int M, int N, int K, int mode)
{
    __shared__ bf16 As[BM][BK];   // unpadded: required by global_load_lds layout
    __shared__ bf16 Bs[BN][BK];
    const int tid  = threadIdx.x;
    const int bn   = blockIdx.x * BN;
    const int bm   = blockIdx.y * BM;
    const int lane = tid & 63;
    const int wave = tid >> 6;
    const int wm   = (wave & 1) * 64;
    const int wn   = (wave >> 1) * 64;

    floatx4 acc[4][4];
    #pragma unroll
    for (int i = 0; i < 4; i++)
        #pragma unroll
        for (int j = 0; j < 4; j++)
            acc[i][j] = (floatx4){0.f, 0.f, 0.f, 0.f};

    const int l8  = lane >> 3;        // 0..7 row within 8-row DMA chunk
    const int c8e = (lane & 7) * 8;   // element col 0,8,..,56

    for (int k0 = 0; k0 < K; k0 += BK) {
        if (Af) {  // layer-0 qkv: fp32 src, inline cvt staging
            const int lr = tid >> 3, lc = (tid & 7) * 8;
            #pragma unroll
            for (int r = 0; r < BM; r += 32) {
                const size_t ra = (size_t)(bm + r + lr) * K + k0 + lc;
                float4 v0 = *(const float4*)(Af + ra);
                float4 v1 = *(const float4*)(Af + ra + 4);
                *(ushort4*)&As[r + lr][lc]     = pack4_bf16(v0);
                *(ushort4*)&As[r + lr][lc + 4] = pack4_bf16(v1);
            }
        } else {
            #pragma unroll
            for (int c = 0; c < 4; ++c) {
                const int rowb = wave * 32 + c * 8;   // wave-uniform LDS base row
                gld16(Ab + (size_t)(bm + rowb + l8) * K + k0 + c8e, &As[rowb][0]);
            }
        }
        #pragma unroll
        for (int c = 0; c < 4; ++c) {
            const int rowb = wave * 32 + c * 8;
            gld16(Bw + (size_t)(bn + rowb + l8) * K + k0 + c8e, &Bs[rowb][0]);
        }
        __syncthreads();
        #pragma unroll
        for (int ks = 0; ks < BK; ks += 32) {
            const int kk = ks + (lane >> 4) * 8;
            const int ri = lane & 15;
            short8 af[4], bfr[4];
            #pragma unroll
            for (int i = 0; i < 4; i++) af[i]  = *(const short8*)&As[wm + i*16 + ri][kk];
            #pragma unroll
            for (int j = 0; j < 4; j++) bfr[j] = *(const short8*)&Bs[wn + j*16 + ri][kk];
            #pragma unroll
            for (int i = 0; i < 4; i++)
                #pragma unroll
                for (int j = 0; j < 4; j++)
                    acc[i][j] = __builtin_amdgcn_mfma_f32_16x16x32_bf16(af[i], bfr[j], acc[i][j], 0, 0, 0);
        }
        __syncthreads();
    }

    // C/D layout: col=lane&15, row=(lane>>4)*4+reg (m89/m91; r5 scalar-core-verified)
    const int cn = lane & 15;
    const int rb = (lane >> 4) * 4;
    #pragma unroll
    for (int j = 0; j < 4; j++) {
        const int col = bn + wn + j * 16 + cn;
        const float bv = bias[col];
        #pragma unroll
        for (int i = 0; i < 4; i++) {
            #pragma unroll
            for (int r = 0; r < 4; r++) {
                const int row = bm + wm + i * 16 + rb + r;
                float v = acc[i][j][r] + bv;
                if (mode == MODE_RELU) {
                    Cb[(size_t)row * N + col] = __float2bfloat16(fmaxf(v, 0.f));
                } else if (mode == MODE_PLAIN) {
                    Cb[(size_t)row * N + col] = __float2bfloat16(v);
                } else {  // QKV scatter -> [B,H,S,dh]
                    const int which = col >> 9;
                    const int f = col & 511;
                    const int h = f >> 6, d = f & 63;
                    const int b = row >> 11, s = row & (SEQ - 1);
                    bf16* dst = (which == 0) ? Qo : (which == 1) ? Ko : Vo;
                    dst[(((size_t)b * NHEAD + h) * SEQ + s) * DH + d] = __float2bfloat16(v);
                }
            }
        }
    }
}

// Block = 4 consecutive queries (same b,h). K/V window + pow2 rows staged in
// LDS once, shared by all 4 waves. Score/softmax/PV logic identical to r11.
__global__ __launch_bounds__(256) void attn_sparse(
    const bf16* __restrict__ Q, const bf16* __restrict__ K,
    const bf16* __restrict__ V, bf16* __restrict__ O)
{
    __shared__ bf16 KL[84][72];   // rows 0..67: window s0-64..s0+3; 68+w*4+j: pow2
    __shared__ bf16 VL[84][72];   // +8 bf16 pad -> 144 B stride (16B-aligned)
    __shared__ float qs[4][64];
    __shared__ float ps[4][80];
    const int tid  = threadIdx.x;
    const int wave = tid >> 6;
    const int lane = tid & 63;
    const int gq0  = blockIdx.x * 4;
    const int s0   = gq0 & (SEQ - 1);
    const int bh   = gq0 >> 11;
    const int s    = s0 + wave;

    const bf16* Kb = K + (size_t)bh * SEQ * DH;
    const bf16* Vb = V + (size_t)bh * SEQ * DH;

    {   // cooperative staging: 84 rows x 128 B, 16 B/thread, 3 passes
        const int c = (tid & 7) * 8;
        #pragma unroll
        for (int pss = 0; pss < 3; ++pss) {
            const int r = (tid >> 3) + 32 * pss;    // 0..95
            if (r < 84) {
                int g;
                if (r < 68) g = s0 - 64 + r;
                else { const int e = r - 68; g = s0 + (e >> 2) - (128 << (e & 3)); }
                if (g >= 0) {
                    *(uint4*)&KL[r][c] = *(const uint4*)(Kb + (size_t)g * DH + c);
                    *(uint4*)&VL[r][c] = *(const uint4*)(Vb + (size_t)g * DH + c);
                }
            }
        }
    }
    qs[wave][lane] = __bfloat162float(Q[((size_t)bh * SEQ + s) * DH + lane]);
    __syncthreads();

    const int kw0 = (s - 64 > 0) ? (s - 64) : 0;
    const int wcount = s - kw0 + 1;            // <= 65
    int nk = wcount;
    #pragma unroll
    for (int st = 128; st <= 1024; st <<= 1)
        if (s - st >= 0) nk++;                  // <= 69

    // LDS row for score index idx: window -> kw0+idx-(s0-64); pow2 j -> 68+wave*4+j
    const float scale = 0.125f;
    float sc0 = -1e30f, sc1 = -1e30f;
    if (lane < nk) {
        const int rr = (lane < wcount) ? (kw0 + lane - s0 + 64) : (68 + wave * 4 + (lane - wcount));
        const bf16* kr = &KL[rr][0];
        float a = 0.f;
        #pragma unroll
        for (int e = 0; e < 64; e++) a += qs[wave][e] * __bfloat162float(kr[e]);
        sc0 = a * scale;
    }
    if (lane + 64 < nk) {
        const int idx = lane + 64;
        const int rr = (idx < wcount) ? (kw0 + idx - s0 + 64) : (68 + wave * 4 + (idx - wcount));
        const bf16* kr = &KL[rr][0];
        float a = 0.f;
        #pragma unroll
        for (int e = 0; e < 64; e++) a += qs[wave][e] * __bfloat162float(kr[e]);
        sc1 = a * scale;
    }

    float m = fmaxf(sc0, sc1);
    #pragma unroll
    for (int off = 32; off; off >>= 1) m = fmaxf(m, __shfl_xor(m, off, 64));
    const float p0 = (lane < nk)      ? __expf(fminf(sc0 - m, 0.f)) : 0.f;
    const float p1 = (lane + 64 < nk) ? __expf(fminf(sc1 - m, 0.f)) : 0.f;
    float lsum = p0 + p1;
    #pragma unroll
    for (int off = 32; off; off >>= 1) lsum += __shfl_xor(lsum, off, 64);
    const float inv = 1.f / fmaxf(lsum, 1e-20f);
    ps[wave][lane] = p0 * inv;
    if (lane + 64 < nk) ps[wave][lane + 64] = p1 * inv;
    __syncthreads();

    float o = 0.f;
    for (int j = 0; j < nk; j++) {
        const int rr = (j < wcount) ? (kw0 + j - s0 + 64) : (68 + wave * 4 + (j - wcount));
        o += ps[wave][j] * __bfloat162float(VL[rr][lane]);
    }

    const int b = bh >> 3, h = bh & 7;
    O[((size_t)(b * SEQ + s)) * D_MODEL + h * DH + lane] = __float2bfloat16(o);
}

// xout = LN(xin + t) * gamma + beta ; t bf16 now. In-place safe.
__global__ __launch_bounds__(256) void ln_residual(
    const bf16* __restrict__ xin_b, const float* __restrict__ xin_f,
    const bf16* __restrict__ t,
    const float* __restrict__ gamma, const float* __restrict__ beta,
    bf16* __restrict__ xout_b, float* __restrict__ xout_f)
{
    const int row = blockIdx.x;
    const int tid = threadIdx.x;
    const size_t base = (size_t)row * D_MODEL;
    float x0, x1;
    if (xin_f != nullptr) {
        x0 = xin_f[base + tid];
        x1 = xin_f[base + tid + 256];
    } else {
        x0 = __bfloat162float(xin_b[base + tid]);
        x1 = __bfloat162float(xin_b[base + tid + 256]);
    }
    const float v0 = x0 + __bfloat162float(t[base + tid]);
    const float v1 = x1 + __bfloat162float(t[base + tid + 256]);
    float sum = v0 + v1;
    float sq  = v0 * v0 + v1 * v1;
    #pragma unroll
    for (int off = 32; off; off >>= 1) {
        sum += __shfl_xor(sum, off, 64);
        sq  += __shfl_xor(sq,  off, 64);
    }
    __shared__ float s1[4], s2[4];
    const int wave = tid >> 6, lane = tid & 63;
    if (lane == 0) { s1[wave] = sum; s2[wave] = sq; }
    __syncthreads();
    const float S1 = s1[0] + s1[1] + s1[2] + s1[3];
    const float S2 = s2[0] + s2[1] + s2[2] + s2[3];
    const float mean = S1 * (1.f / D_MODEL);
    const float var  = fmaxf(S2 * (1.f / D_MODEL) - mean * mean, 0.f);
    const float r    = rsqrtf(var + 1e-5f);
    const float o0 = (v0 - mean) * r * gamma[tid] + beta[tid];
    const float o1 = (v1 - mean) * r * gamma[tid + 256] + beta[tid + 256];
    if (xout_f != nullptr) {
        xout_f[base + tid]       = o0;
        xout_f[base + tid + 256] = o1;
    } else {
        xout_b[base + tid]       = __float2bfloat16(o0);
        xout_b[base + tid + 256] = __float2bfloat16(o1);
    }
}

extern "C" void kernel_launch(void* const* d_in, const int* in_sizes, int n_in,
                              void* d_out, int out_size, void* d_ws, size_t ws_size,
                              hipStream_t stream)
{
    const int want[12] = {1572864, 3072, 524288, 1024, 1024, 1024,
                          2097152, 4096, 2097152, 1024, 1024, 1024};
    int anchor = -1;
    for (int a = 2; a >= 1; --a) {
        if (n_in < a + 12) continue;
        bool ok = true;
        for (int i = 0; i < 12; i++) if (in_sizes[a + i] != want[i]) { ok = false; break; }
        if (ok) { anchor = a; break; }
    }
    if (anchor < 0) return;

    const float* src   = (const float*)d_in[0];
    const float* qkv_w = (const float*)d_in[anchor + 0];
    const float* qkv_b = (const float*)d_in[anchor + 1];
    const float* out_w = (const float*)d_in[anchor + 2];
    const float* out_b = (const float*)d_in[anchor + 3];
    const float* ln1_s = (const float*)d_in[anchor + 4];
    const float* ln1_b = (const float*)d_in[anchor + 5];
    const float* w1    = (const float*)d_in[anchor + 6];
    const float* b1    = (const float*)d_in[anchor + 7];
    const float* w2    = (const float*)d_in[anchor + 8];
    const float* b2    = (const float*)d_in[anchor + 9];
    const float* ln2_s = (const float*)d_in[anchor + 10];
    const float* ln2_b = (const float*)d_in[anchor + 11];
    float* out = (float*)d_out;   // fp32 output

    // 60 MiB of the proven-safe 64 MiB:
    // [0,32) Q/K/V/O union Hb; [32,40) Tb bf16; [40,48) xA; [48,60) bf16 weights.
    constexpr size_t MiB = 1024 * 1024;
    if (ws_size < 64 * MiB) return;
    char* p = (char*)d_ws;
    bf16*  Q   = (bf16*)(p);
    bf16*  Kt  = (bf16*)(p + 8 * MiB);
    bf16*  V   = (bf16*)(p + 16 * MiB);
    bf16*  O   = (bf16*)(p + 24 * MiB);
    bf16*  Hb  = (bf16*)(p);                 // 32 MiB alias (disjoint lifetimes)
    bf16*  Tb  = (bf16*)(p + 32 * MiB);
    bf16*  xA  = (bf16*)(p + 40 * MiB);
    bf16*  qwB = (bf16*)(p + 48 * MiB);      // 3 MiB
    bf16*  owB = (bf16*)(p + 51 * MiB);      // 1 MiB
    bf16*  w1B = (bf16*)(p + 52 * MiB);      // 4 MiB
    bf16*  w2B = (bf16*)(p + 56 * MiB);      // 4 MiB

    auto cvt = [&](const float* s, bf16* d, int n) {
        cvt_f32_bf16<<<dim3((n / 4 + 255) / 256), 256, 0, stream>>>(s, d, n);
    };
    cvt(qkv_w, qwB, NLAYERS * 3 * D_MODEL * D_MODEL);
    cvt(out_w, owB, NLAYERS * D_MODEL * D_MODEL);
    cvt(w1,    w1B, NLAYERS * D_FF * D_MODEL);
    cvt(w2,    w2B, NLAYERS * D_MODEL * D_FF);

    for (int l = 0; l < NLAYERS; ++l) {
        const bf16*  xb = (l == 0) ? nullptr : xA;
        const float* xf = (l == 0) ? src : nullptr;
        gemm_bt<<<dim3((3 * D_MODEL) / BN, ROWS / BM), 256, 0, stream>>>(
            xb, xf, qwB + (size_t)l * 3 * D_MODEL * D_MODEL, qkv_b + (size_t)l * 3 * D_MODEL,
            nullptr, Q, Kt, V, ROWS, 3 * D_MODEL, D_MODEL, MODE_QKV);
        attn_sparse<<<dim3(BATCH * NHEAD * SEQ / 4), 256, 0, stream>>>(Q, Kt, V, O);
        gemm_bt<<<dim3(D_MODEL / BN, ROWS / BM), 256, 0, stream>>>(
            O, nullptr, owB + (size_t)l * D_MODEL * D_MODEL, out_b + (size_t)l * D_MODEL,
            Tb, nullptr, nullptr, nullptr, ROWS, D_MODEL, D_MODEL, MODE_PLAIN);
        ln_residual<<<dim3(ROWS), 256, 0, stream>>>(
            xb, xf, Tb, ln1_s + (size_t)l * D_MODEL, ln1_b + (size_t)l * D_MODEL,
            xA, nullptr);                                // in-place for l=1 (safe)
        gemm_bt<<<dim3(D_FF / BN, ROWS / BM), 256, 0, stream>>>(
            xA, nullptr, w1B + (size_t)l * D_FF * D_MODEL, b1 + (size_t)l * D_FF,
            Hb, nullptr, nullptr, nullptr, ROWS, D_FF, D_MODEL, MODE_RELU);
        gemm_bt<<<dim3(D_MODEL / BN, ROWS / BM), 256, 0, stream>>>(
            Hb, nullptr, w2B + (size_t)l * D_MODEL * D_FF, b2 + (size_t)l * D_MODEL,
            Tb, nullptr, nullptr, nullptr, ROWS, D_MODEL, D_FF, MODE_PLAIN);
        if (l == NLAYERS - 1) {
            ln_residual<<<dim3(ROWS), 256, 0, stream>>>(
                xA, nullptr, Tb, ln2_s + (size_t)l * D_MODEL, ln2_b + (size_t)l * D_MODEL,
                nullptr, out);                           // final: fp32 -> d_out
        } else {
            ln_residual<<<dim3(ROWS), 256, 0, stream>>>(
                xA, nullptr, Tb, ln2_s + (size_t)l * D_MODEL, ln2_b + (size_t)l * D_MODEL,
                xA, nullptr);                            // in-place (safe)
        }
    }
}

// Round 13
// 539.624 us; speedup vs baseline: 1.7187x; 1.0870x over previous
//
#include <hip/hip_runtime.h>
#include <hip/hip_bf16.h>
#include <cstdint>
#include <cstddef>

using bf16 = __hip_bfloat16;

typedef __attribute__((ext_vector_type(8))) short short8;
typedef __attribute__((ext_vector_type(4))) float floatx4;

constexpr int NLAYERS = 2;
constexpr int D_MODEL = 512;
constexpr int NHEAD   = 8;
constexpr int DH      = 64;
constexpr int SEQ     = 2048;
constexpr int BATCH   = 4;
constexpr int D_FF    = 2048;
constexpr int ROWS    = BATCH * SEQ;  // 8192

#define MODE_QKV   0
#define MODE_RELU  1
#define MODE_PLAIN 2

constexpr int BM = 128, BN = 128, BK = 64;

__device__ inline ushort4 pack4_bf16(float4 v) {
    ushort4 u;
    u.x = __bfloat16_as_ushort(__float2bfloat16(v.x));
    u.y = __bfloat16_as_ushort(__float2bfloat16(v.y));
    u.z = __bfloat16_as_ushort(__float2bfloat16(v.z));
    u.w = __bfloat16_as_ushort(__float2bfloat16(v.w));
    return u;
}

__device__ inline void gld16(const void* g, void* l) {
    __builtin_amdgcn_global_load_lds(
        (const __attribute__((address_space(1))) void*)(uintptr_t)g,
        (__attribute__((address_space(3))) void*)(uint32_t)(uintptr_t)l,
        16, 0, 0);
}

__global__ __launch_bounds__(256) void cvt_f32_bf16(
    const float* __restrict__ in, bf16* __restrict__ outp, int n)
{
    const int i = (blockIdx.x * 256 + threadIdx.x) * 4;
    if (i + 3 < n) {
        *(ushort4*)(outp + i) = pack4_bf16(*(const float4*)(in + i));
    } else {
        for (int j = i; j < n; j++) outp[j] = __float2bfloat16(in[j]);
    }
}

// C[M,N] = A[M,K] @ B[N,K]^T + bias (unchanged from r12).
__global__ __launch_bounds__(256) void gemm_bt(
    const bf16* __restrict__ Ab, const float* __restrict__ Af,
    const bf16* __restrict__ Bw, const float* __restrict__ bias,
    bf16* __restrict__ Cb,
    bf16* __restrict__ Qo, bf16* __restrict__ Ko, bf16* __restrict__ Vo,
    int M, int N, int K, int mode)
{
    __shared__ bf16 As[BM][BK];
    __shared__ bf16 Bs[BN][BK];
    const int tid  = threadIdx.x;
    const int bn   = blockIdx.x * BN;
    const int bm   = blockIdx.y * BM;
    const int lane = tid & 63;
    const int wave = tid >> 6;
    const int wm   = (wave & 1) * 64;
    const int wn   = (wave >> 1) * 64;

    floatx4 acc[4][4];
    #pragma unroll
    for (int i = 0; i < 4; i++)
        #pragma unroll
        for (int j = 0; j < 4; j++)
            acc[i][j] = (floatx4){0.f, 0.f, 0.f, 0.f};

    const int l8  = lane >> 3;
    const int c8e = (lane & 7) * 8;

    for (int k0 = 0; k0 < K; k0 += BK) {
        if (Af) {
            const int lr = tid >> 3, lc = (tid & 7) * 8;
            #pragma unroll
            for (int r = 0; r < BM; r += 32) {
                const size_t ra = (size_t)(bm + r + lr) * K + k0 + lc;
                float4 v0 = *(const float4*)(Af + ra);
                float4 v1 = *(const float4*)(Af + ra + 4);
                *(ushort4*)&As[r + lr][lc]     = pack4_bf16(v0);
                *(ushort4*)&As[r + lr][lc + 4] = pack4_bf16(v1);
            }
        } else {
            #pragma unroll
            for (int c = 0; c < 4; ++c) {
                const int rowb = wave * 32 + c * 8;
                gld16(Ab + (size_t)(bm + rowb + l8) * K + k0 + c8e, &As[rowb][0]);
            }
        }
        #pragma unroll
        for (int c = 0; c < 4; ++c) {
            const int rowb = wave * 32 + c * 8;
            gld16(Bw + (size_t)(bn + rowb + l8) * K + k0 + c8e, &Bs[rowb][0]);
        }
        __syncthreads();
        #pragma unroll
        for (int ks = 0; ks < BK; ks += 32) {
            const int kk = ks + (lane >> 4) * 8;
            const int ri = lane & 15;
            short8 af[4], bfr[4];
            #pragma unroll
            for (int i = 0; i < 4; i++) af[i]  = *(const short8*)&As[wm + i*16 + ri][kk];
            #pragma unroll
            for (int j = 0; j < 4; j++) bfr[j] = *(const short8*)&Bs[wn + j*16 + ri][kk];
            #pragma unroll
            for (int i = 0; i < 4; i++)
                #pragma unroll
                for (int j = 0; j < 4; j++)
                    acc[i][j] = __builtin_amdgcn_mfma_f32_16x16x32_bf16(af[i], bfr[j], acc[i][j], 0, 0, 0);
        }
        __syncthreads();
    }

    const int cn = lane & 15;
    const int rb = (lane >> 4) * 4;
    #pragma unroll
    for (int j = 0; j < 4; j++) {
        const int col = bn + wn + j * 16 + cn;
        const float bv = bias[col];
        #pragma unroll
        for (int i = 0; i < 4; i++) {
            #pragma unroll
            for (int r = 0; r < 4; r++) {
                const int row = bm + wm + i * 16 + rb + r;
                float v = acc[i][j][r] + bv;
                if (mode == MODE_RELU) {
                    Cb[(size_t)row * N + col] = __float2bfloat16(fmaxf(v, 0.f));
                } else if (mode == MODE_PLAIN) {
                    Cb[(size_t)row * N + col] = __float2bfloat16(v);
                } else {
                    const int which = col >> 9;
                    const int f = col & 511;
                    const int h = f >> 6, d = f & 63;
                    const int b = row >> 11, s = row & (SEQ - 1);
                    bf16* dst = (which == 0) ? Qo : (which == 1) ? Ko : Vo;
                    dst[(((size_t)b * NHEAD + h) * SEQ + s) * DH + d] = __float2bfloat16(v);
                }
            }
        }
    }
}

// MFMA attention. Block = 16 consecutive queries of one (b,h).
// Key union (144 rows): r<80 -> window g=s0-64+r; r>=80 -> e=r-80,
// g = s0+(e&15)-(128<<(e>>4)). S=QK^T via MFMA -> SL fp32 -> masked softmax
// -> PL bf16 (padded to 160) -> O=P.V^T via MFMA.
__global__ __launch_bounds__(256) void attn_mfma(
    const bf16* __restrict__ Q, const bf16* __restrict__ K,
    const bf16* __restrict__ V, bf16* __restrict__ O)
{
    __shared__ bf16  QL[16][72];
    __shared__ bf16  KL[144][72];
    __shared__ bf16  VT[64][176];    // dims x keys (transposed), cols 144..159 zeroed
    __shared__ float SL[16][148];
    __shared__ bf16  PL[16][176];    // cols 144..159 zeroed
    const int tid  = threadIdx.x;
    const int wave = tid >> 6;
    const int lane = tid & 63;
    const int gq0  = blockIdx.x * 16;
    const int s0   = gq0 & (SEQ - 1);
    const int bh   = gq0 >> 11;

    const bf16* Kb = K + (size_t)bh * SEQ * DH;
    const bf16* Vb = V + (size_t)bh * SEQ * DH;

    // --- stage QL ---
    if (tid < 128) {
        const int r = tid >> 3, c = (tid & 7) * 8;
        *(uint4*)&QL[r][c] = *(const uint4*)(Q + ((size_t)bh * SEQ + s0 + r) * DH + c);
    }
    // --- stage KL + VT (transpose), zero for g<0 ---
    for (int idx = tid; idx < 144 * 8; idx += 256) {
        const int r = idx >> 3;
        const int c = (idx & 7) * 8;
        int g;
        if (r < 80) g = s0 - 64 + r;
        else { const int e = r - 80; g = s0 + (e & 15) - (128 << (e >> 4)); }
        uint4 kv = {0, 0, 0, 0};
        uint4 vv = {0, 0, 0, 0};
        if (g >= 0) {
            kv = *(const uint4*)(Kb + (size_t)g * DH + c);
            vv = *(const uint4*)(Vb + (size_t)g * DH + c);
        }
        *(uint4*)&KL[r][c] = kv;
        const bf16* ve = (const bf16*)&vv;
        #pragma unroll
        for (int t2 = 0; t2 < 8; t2++) VT[c + t2][r] = ve[t2];
    }
    // --- zero pads: VT[.][144..159], PL[.][144..159] ---
    for (int idx = tid; idx < 64 * 16; idx += 256)
        VT[idx >> 4][144 + (idx & 15)] = __float2bfloat16(0.f);
    PL[tid >> 4][144 + (tid & 15)] = __float2bfloat16(0.f);
    __syncthreads();

    // --- S = Q.K^T * scale (9 n-tiles, k=64 in 2 steps) ---
    {
        const int kk = (lane >> 4) * 8;
        const int ri = lane & 15;
        const int cn = lane & 15;
        const int rb = (lane >> 4) * 4;
        short8 a0 = *(const short8*)&QL[ri][kk];
        short8 a1 = *(const short8*)&QL[ri][kk + 32];
        for (int t = wave; t < 9; t += 4) {
            floatx4 acc = (floatx4){0.f, 0.f, 0.f, 0.f};
            short8 b0 = *(const short8*)&KL[t * 16 + ri][kk];
            short8 b1 = *(const short8*)&KL[t * 16 + ri][kk + 32];
            acc = __builtin_amdgcn_mfma_f32_16x16x32_bf16(a0, b0, acc, 0, 0, 0);
            acc = __builtin_amdgcn_mfma_f32_16x16x32_bf16(a1, b1, acc, 0, 0, 0);
            #pragma unroll
            for (int r2 = 0; r2 < 4; r2++)
                SL[rb + r2][t * 16 + cn] = acc[r2] * 0.125f;
        }
    }
    __syncthreads();

    // --- masked softmax: wave handles queries 4w..4w+3 ---
    #pragma unroll
    for (int q4 = 0; q4 < 4; q4++) {
        const int q = wave * 4 + q4;
        const int s = s0 + q;
        float sc[3];
        bool  val[3];
        #pragma unroll
        for (int u = 0; u < 3; u++) {
            const int slot = lane + 64 * u;
            bool v = false;
            if (slot < 144) {
                if (slot < 80) {
                    const int g = s0 - 64 + slot;
                    v = (g >= 0) && (slot >= q) && (slot <= q + 64);
                } else {
                    const int e = slot - 80;
                    v = ((e & 15) == q) && (s - (128 << (e >> 4)) >= 0);
                }
            }
            val[u] = v;
            sc[u] = v ? SL[q][slot] : -1e30f;
        }
        float m = fmaxf(sc[0], fmaxf(sc[1], sc[2]));
        #pragma unroll
        for (int off = 32; off; off >>= 1) m = fmaxf(m, __shfl_xor(m, off, 64));
        float pv[3];
        float lsum = 0.f;
        #pragma unroll
        for (int u = 0; u < 3; u++) {
            pv[u] = val[u] ? __expf(fminf(sc[u] - m, 0.f)) : 0.f;
            lsum += pv[u];
        }
        #pragma unroll
        for (int off = 32; off; off >>= 1) lsum += __shfl_xor(lsum, off, 64);
        const float inv = 1.f / fmaxf(lsum, 1e-20f);
        #pragma unroll
        for (int u = 0; u < 3; u++) {
            const int slot = lane + 64 * u;
            if (slot < 144) PL[q][slot] = __float2bfloat16(pv[u] * inv);
        }
    }
    __syncthreads();

    // --- O = P.V^T (wave w -> dim tile w; k=160 in 5 steps) ---
    {
        const int kk = (lane >> 4) * 8;
        const int ri = lane & 15;
        floatx4 acc = (floatx4){0.f, 0.f, 0.f, 0.f};
        #pragma unroll
        for (int ks = 0; ks < 160; ks += 32) {
            short8 a = *(const short8*)&PL[ri][ks + kk];
            short8 b = *(const short8*)&VT[wave * 16 + ri][ks + kk];
            acc = __builtin_amdgcn_mfma_f32_16x16x32_bf16(a, b, acc, 0, 0, 0);
        }
        const int cn = lane & 15;
        const int rb = (lane >> 4) * 4;
        const int b  = bh >> 3, h = bh & 7;
        #pragma unroll
        for (int r2 = 0; r2 < 4; r2++)
            O[((size_t)(b * SEQ + s0 + rb + r2)) * D_MODEL + h * DH + wave * 16 + cn]
                = __float2bfloat16(acc[r2]);
    }
}

// xout = LN(xin + t) * gamma + beta (unchanged from r12).
__global__ __launch_bounds__(256) void ln_residual(
    const bf16* __restrict__ xin_b, const float* __restrict__ xin_f,
    const bf16* __restrict__ t,
    const float* __restrict__ gamma, const float* __restrict__ beta,
    bf16* __restrict__ xout_b, float* __restrict__ xout_f)
{
    const int row = blockIdx.x;
    const int tid = threadIdx.x;
    const size_t base = (size_t)row * D_MODEL;
    float x0, x1;
    if (xin_f != nullptr) {
        x0 = xin_f[base + tid];
        x1 = xin_f[base + tid + 256];
    } else {
        x0 = __bfloat162float(xin_b[base + tid]);
        x1 = __bfloat162float(xin_b[base + tid + 256]);
    }
    const float v0 = x0 + __bfloat162float(t[base + tid]);
    const float v1 = x1 + __bfloat162float(t[base + tid + 256]);
    float sum = v0 + v1;
    float sq  = v0 * v0 + v1 * v1;
    #pragma unroll
    for (int off = 32; off; off >>= 1) {
        sum += __shfl_xor(sum, off, 64);
        sq  += __shfl_xor(sq,  off, 64);
    }
    __shared__ float s1[4], s2[4];
    const int wave = tid >> 6, lane = tid & 63;
    if (lane == 0) { s1[wave] = sum; s2[wave] = sq; }
    __syncthreads();
    const float S1 = s1[0] + s1[1] + s1[2] + s1[3];
    const float S2 = s2[0] + s2[1] + s2[2] + s2[3];
    const float mean = S1 * (1.f / D_MODEL);
    const float var  = fmaxf(S2 * (1.f / D_MODEL) - mean * mean, 0.f);
    const float r    = rsqrtf(var + 1e-5f);
    const float o0 = (v0 - mean) * r * gamma[tid] + beta[tid];
    const float o1 = (v1 - mean) * r * gamma[tid + 256] + beta[tid + 256];
    if (xout_f != nullptr) {
        xout_f[base + tid]       = o0;
        xout_f[base + tid + 256] = o1;
    } else {
        xout_b[base + tid]       = __float2bfloat16(o0);
        xout_b[base + tid + 256] = __float2bfloat16(o1);
    }
}

extern "C" void kernel_launch(void* const* d_in, const int* in_sizes, int n_in,
                              void* d_out, int out_size, void* d_ws, size_t ws_size,
                              hipStream_t stream)
{
    const int want[12] = {1572864, 3072, 524288, 1024, 1024, 1024,
                          2097152, 4096, 2097152, 1024, 1024, 1024};
    int anchor = -1;
    for (int a = 2; a >= 1; --a) {
        if (n_in < a + 12) continue;
        bool ok = true;
        for (int i = 0; i < 12; i++) if (in_sizes[a + i] != want[i]) { ok = false; break; }
        if (ok) { anchor = a; break; }
    }
    if (anchor < 0) return;

    const float* src   = (const float*)d_in[0];
    const float* qkv_w = (const float*)d_in[anchor + 0];
    const float* qkv_b = (const float*)d_in[anchor + 1];
    const float* out_w = (const float*)d_in[anchor + 2];
    const float* out_b = (const float*)d_in[anchor + 3];
    const float* ln1_s = (const float*)d_in[anchor + 4];
    const float* ln1_b = (const float*)d_in[anchor + 5];
    const float* w1    = (const float*)d_in[anchor + 6];
    const float* b1    = (const float*)d_in[anchor + 7];
    const float* w2    = (const float*)d_in[anchor + 8];
    const float* b2    = (const float*)d_in[anchor + 9];
    const float* ln2_s = (const float*)d_in[anchor + 10];
    const float* ln2_b = (const float*)d_in[anchor + 11];
    float* out = (float*)d_out;

    constexpr size_t MiB = 1024 * 1024;
    if (ws_size < 64 * MiB) return;
    char* p = (char*)d_ws;
    bf16*  Q   = (bf16*)(p);
    bf16*  Kt  = (bf16*)(p + 8 * MiB);
    bf16*  V   = (bf16*)(p + 16 * MiB);
    bf16*  O   = (bf16*)(p + 24 * MiB);
    bf16*  Hb  = (bf16*)(p);                 // 32 MiB alias (disjoint lifetimes)
    bf16*  Tb  = (bf16*)(p + 32 * MiB);
    bf16*  xA  = (bf16*)(p + 40 * MiB);
    bf16*  qwB = (bf16*)(p + 48 * MiB);
    bf16*  owB = (bf16*)(p + 51 * MiB);
    bf16*  w1B = (bf16*)(p + 52 * MiB);
    bf16*  w2B = (bf16*)(p + 56 * MiB);

    auto cvt = [&](const float* s, bf16* d, int n) {
        cvt_f32_bf16<<<dim3((n / 4 + 255) / 256), 256, 0, stream>>>(s, d, n);
    };
    cvt(qkv_w, qwB, NLAYERS * 3 * D_MODEL * D_MODEL);
    cvt(out_w, owB, NLAYERS * D_MODEL * D_MODEL);
    cvt(w1,    w1B, NLAYERS * D_FF * D_MODEL);
    cvt(w2,    w2B, NLAYERS * D_MODEL * D_FF);

    for (int l = 0; l < NLAYERS; ++l) {
        const bf16*  xb = (l == 0) ? nullptr : xA;
        const float* xf = (l == 0) ? src : nullptr;
        gemm_bt<<<dim3((3 * D_MODEL) / BN, ROWS / BM), 256, 0, stream>>>(
            xb, xf, qwB + (size_t)l * 3 * D_MODEL * D_MODEL, qkv_b + (size_t)l * 3 * D_MODEL,
            nullptr, Q, Kt, V, ROWS, 3 * D_MODEL, D_MODEL, MODE_QKV);
        attn_mfma<<<dim3(BATCH * NHEAD * SEQ / 16), 256, 0, stream>>>(Q, Kt, V, O);
        gemm_bt<<<dim3(D_MODEL / BN, ROWS / BM), 256, 0, stream>>>(
            O, nullptr, owB + (size_t)l * D_MODEL * D_MODEL, out_b + (size_t)l * D_MODEL,
            Tb, nullptr, nullptr, nullptr, ROWS, D_MODEL, D_MODEL, MODE_PLAIN);
        ln_residual<<<dim3(ROWS), 256, 0, stream>>>(
            xb, xf, Tb, ln1_s + (size_t)l * D_MODEL, ln1_b + (size_t)l * D_MODEL,
            xA, nullptr);
        gemm_bt<<<dim3(D_FF / BN, ROWS / BM), 256, 0, stream>>>(
            xA, nullptr, w1B + (size_t)l * D_FF * D_MODEL, b1 + (size_t)l * D_FF,
            Hb, nullptr, nullptr, nullptr, ROWS, D_FF, D_MODEL, MODE_RELU);
        gemm_bt<<<dim3(D_MODEL / BN, ROWS / BM), 256, 0, stream>>>(
            Hb, nullptr, w2B + (size_t)l * D_MODEL * D_FF, b2 + (size_t)l * D_MODEL,
            Tb, nullptr, nullptr, nullptr, ROWS, D_MODEL, D_FF, MODE_PLAIN);
        if (l == NLAYERS - 1) {
            ln_residual<<<dim3(ROWS), 256, 0, stream>>>(
                xA, nullptr, Tb, ln2_s + (size_t)l * D_MODEL, ln2_b + (size_t)l * D_MODEL,
                nullptr, out);
        } else {
            ln_residual<<<dim3(ROWS), 256, 0, stream>>>(
                xA, nullptr, Tb, ln2_s + (size_t)l * D_MODEL, ln2_b + (size_t)l * D_MODEL,
                xA, nullptr);
        }
    }
}